// Round 1
// baseline (1328.925 us; speedup 1.0000x reference)
//
#include <hip/hip_runtime.h>

#define D 200
#define RRELU_SLOPE 0.22916666666666666f

__device__ __forceinline__ float rrelu(float x) {
    return x >= 0.0f ? x : x * RRELU_SLOPE;
}

// ---- CSR build ----------------------------------------------------------

__global__ void hist_k(const int* __restrict__ dst, int* __restrict__ counts, int E) {
    int e = blockIdx.x * blockDim.x + threadIdx.x;
    if (e < E) atomicAdd(&counts[dst[e]], 1);
}

// single-block exclusive scan over n counts -> offsets[0..n]
__global__ void scan_k(const int* __restrict__ counts, int* __restrict__ offsets, int n) {
    __shared__ int tmp[1024];
    __shared__ int carry;
    if (threadIdx.x == 0) carry = 0;
    __syncthreads();
    for (int base = 0; base < n; base += 1024) {
        int i = base + threadIdx.x;
        int v = (i < n) ? counts[i] : 0;
        tmp[threadIdx.x] = v;
        __syncthreads();
        for (int off = 1; off < 1024; off <<= 1) {
            int t = (threadIdx.x >= off) ? tmp[threadIdx.x - off] : 0;
            __syncthreads();
            tmp[threadIdx.x] += t;
            __syncthreads();
        }
        int incl = tmp[threadIdx.x];
        int c = carry;
        if (i < n) offsets[i] = c + incl - v;   // exclusive
        __syncthreads();
        if (threadIdx.x == 1023) carry = c + tmp[1023];
        __syncthreads();
    }
    if (threadIdx.x == 0) offsets[n] = carry;
}

__global__ void cursor_k(const int* __restrict__ offsets, const int* __restrict__ counts,
                         int* __restrict__ cursor, int* __restrict__ noin,
                         int* __restrict__ noin_cnt, int n) {
    int v = blockIdx.x * blockDim.x + threadIdx.x;
    if (v < n) {
        cursor[v] = offsets[v];
        if (counts[v] == 0) {
            int p = atomicAdd(noin_cnt, 1);
            noin[p] = v;
        }
    }
}

__global__ void scatter_k(const int* __restrict__ dst, int* __restrict__ cursor,
                          int* __restrict__ perm, int E) {
    int e = blockIdx.x * blockDim.x + threadIdx.x;
    if (e < E) {
        int p = atomicAdd(&cursor[dst[e]], 1);
        perm[p] = e;
    }
}

// ---- h0 = init_ent_emb[node_id] ----------------------------------------

__global__ void gather_k(const float* __restrict__ init, const int* __restrict__ nid,
                         float* __restrict__ h0) {
    int v = blockIdx.x;
    int d = threadIdx.x;
    if (d < D) h0[(size_t)v * D + d] = init[(size_t)nid[v] * D + d];
}

// ---- per-layer segment aggregation: aggn[v] = norm[v] * sum_e (h[src]+rel[etype])

__global__ void agg_k(const float* __restrict__ h, const float* __restrict__ rel,
                      const int* __restrict__ src, const int* __restrict__ etype,
                      const int* __restrict__ perm, const int* __restrict__ offsets,
                      const float* __restrict__ norm, float* __restrict__ aggn) {
    int v = blockIdx.x;
    int d = threadIdx.x;
    int beg = offsets[v], end = offsets[v + 1];
    float acc = 0.0f;
    for (int i = beg; i < end; ++i) {
        int e = perm[i];
        int s = src[e];
        int r = etype[e];
        if (d < D) acc += h[(size_t)s * D + d] + rel[(size_t)r * D + d];
    }
    if (d < D) aggn[(size_t)v * D + d] = acc * norm[v];
}

// ---- fused GEMM + epilogue: out = rrelu(Ag @ Wn + H @ Wl) --------------
// M x 400 x 200; tile 64x64, 256 threads, 4x4 per thread.

__global__ __launch_bounds__(256) void gemm_k(
        const float* __restrict__ Ag, const float* __restrict__ H,
        const float* __restrict__ Wn, const float* __restrict__ Wl,
        float* __restrict__ out, int M) {
    // As transposed: [kk][row], stride 68 floats (272B, multiple of 16B)
    __shared__ float As[16][68];
    __shared__ float Bs[16][64];
    int tid = threadIdx.x;
    int tx = tid & 15;          // col group
    int ty = tid >> 4;          // row group
    int rowBase = blockIdx.x * 64;
    int colBase = blockIdx.y * 64;
    float acc[4][4] = {};

    for (int k0 = 0; k0 < 400; k0 += 16) {
        // stage A: 64 rows x 16 k, store transposed
#pragma unroll
        for (int p = 0; p < 4; ++p) {
            int idx = p * 256 + tid;
            int r = idx >> 4;
            int kk = idx & 15;
            int row = rowBase + r;
            int k = k0 + kk;
            float v = 0.0f;
            if (row < M)
                v = (k < 200) ? Ag[(size_t)row * 200 + k]
                              : H[(size_t)row * 200 + (k - 200)];
            As[kk][r] = v;
        }
        // stage B: 16 k x 64 cols
#pragma unroll
        for (int p = 0; p < 4; ++p) {
            int idx = p * 256 + tid;
            int kk = idx >> 6;
            int c = idx & 63;
            int k = k0 + kk;
            int col = colBase + c;
            float v = 0.0f;
            if (col < 200)
                v = (k < 200) ? Wn[(size_t)k * 200 + col]
                              : Wl[(size_t)(k - 200) * 200 + col];
            Bs[kk][c] = v;
        }
        __syncthreads();
#pragma unroll
        for (int kk = 0; kk < 16; ++kk) {
            float4 av = *(const float4*)&As[kk][ty * 4];
            float4 bv = *(const float4*)&Bs[kk][tx * 4];
            float a[4] = {av.x, av.y, av.z, av.w};
            float b[4] = {bv.x, bv.y, bv.z, bv.w};
#pragma unroll
            for (int i = 0; i < 4; ++i)
#pragma unroll
                for (int j = 0; j < 4; ++j)
                    acc[i][j] += a[i] * b[j];
        }
        __syncthreads();
    }
    int col = colBase + tx * 4;
    if (col < 200) {
#pragma unroll
        for (int i = 0; i < 4; ++i) {
            int row = rowBase + ty * 4 + i;
            if (row < M) {
                float4 o;
                o.x = rrelu(acc[i][0]);
                o.y = rrelu(acc[i][1]);
                o.z = rrelu(acc[i][2]);
                o.w = rrelu(acc[i][3]);
                *(float4*)&out[(size_t)row * 200 + col] = o;
            }
        }
    }
}

// ---- fixup for in-degree-0 nodes: out[v] = rrelu(h[v] @ We) ------------

__global__ void fixup_k(const float* __restrict__ h, const float* __restrict__ We,
                        const int* __restrict__ noin, const int* __restrict__ noin_cnt,
                        float* __restrict__ out) {
    int cnt = *noin_cnt;
    for (int i = blockIdx.x; i < cnt; i += gridDim.x) {
        int v = noin[i];
        int j = threadIdx.x;
        if (j < D) {
            float acc = 0.0f;
            for (int k = 0; k < D; ++k)
                acc += h[(size_t)v * D + k] * We[(size_t)k * D + j];
            out[(size_t)v * D + j] = rrelu(acc);
        }
    }
}

extern "C" void kernel_launch(void* const* d_in, const int* in_sizes, int n_in,
                              void* d_out, int out_size, void* d_ws, size_t ws_size,
                              hipStream_t stream) {
    const float* init  = (const float*)d_in[0];
    const float* rel   = (const float*)d_in[1];
    const float* Wn    = (const float*)d_in[2];   // [L,D,D]
    const float* Wl    = (const float*)d_in[3];
    const float* We    = (const float*)d_in[4];
    const float* norm  = (const float*)d_in[5];
    const int* src     = (const int*)d_in[6];
    const int* dst     = (const int*)d_in[7];
    const int* etype   = (const int*)d_in[8];
    const int* node_id = (const int*)d_in[9];
    float* out = (float*)d_out;

    int N = in_sizes[5];
    int E = in_sizes[6];

    // workspace carve
    char* w = (char*)d_ws;
    float* aggn = (float*)w;  w += (size_t)N * D * sizeof(float);
    float* h1   = (float*)w;  w += (size_t)N * D * sizeof(float);
    int* counts  = (int*)w;   w += (size_t)N * sizeof(int);
    int* offsets = (int*)w;   w += (size_t)(N + 1) * sizeof(int);
    int* cursor  = (int*)w;   w += (size_t)N * sizeof(int);
    int* perm    = (int*)w;   w += (size_t)E * sizeof(int);
    int* noin    = (int*)w;   w += (size_t)N * sizeof(int);
    int* noin_cnt = (int*)w;  w += sizeof(int);

    hipMemsetAsync(counts, 0, (size_t)N * sizeof(int), stream);
    hipMemsetAsync(noin_cnt, 0, sizeof(int), stream);

    hist_k<<<(E + 255) / 256, 256, 0, stream>>>(dst, counts, E);
    scan_k<<<1, 1024, 0, stream>>>(counts, offsets, N);
    cursor_k<<<(N + 255) / 256, 256, 0, stream>>>(offsets, counts, cursor, noin, noin_cnt, N);
    scatter_k<<<(E + 255) / 256, 256, 0, stream>>>(dst, cursor, perm, E);

    // h0 -> d_out
    gather_k<<<N, 256, 0, stream>>>(init, node_id, out);

    dim3 gg((N + 63) / 64, 4);

    // layer 0: read h0 (=out), write h1
    agg_k<<<N, 256, 0, stream>>>(out, rel, src, etype, perm, offsets, norm, aggn);
    gemm_k<<<gg, 256, 0, stream>>>(aggn, out, Wn, Wl, h1, N);
    fixup_k<<<64, 256, 0, stream>>>(out, We, noin, noin_cnt, h1);

    // layer 1: read h1, write out
    agg_k<<<N, 256, 0, stream>>>(h1, rel, src, etype, perm, offsets, norm, aggn);
    gemm_k<<<gg, 256, 0, stream>>>(aggn, h1, Wn + D * D, Wl + D * D, out, N);
    fixup_k<<<64, 256, 0, stream>>>(h1, We + D * D, noin, noin_cnt, out);
}

// Round 2
// 625.508 us; speedup vs baseline: 2.1246x; 2.1246x over previous
//
#include <hip/hip_runtime.h>

#define D 200
#define RRELU_SLOPE 0.22916666666666666f
#define SCAN_B 1024

typedef unsigned short u16;
typedef unsigned int u32;

using bf16x8 = __attribute__((ext_vector_type(8))) short;
using f32x4  = __attribute__((ext_vector_type(4))) float;

__device__ __forceinline__ float rrelu(float x) {
    return x >= 0.0f ? x : x * RRELU_SLOPE;
}
__device__ __forceinline__ float bf2f(u32 u) {
    union { u32 i; float f; } c; c.i = u << 16; return c.f;
}
__device__ __forceinline__ u32 f2bf(float f) {
    union { float f; u32 i; } c; c.f = f;
    return (c.i + 0x7fffu + ((c.i >> 16) & 1u)) >> 16;
}

// ---- CSR build ----------------------------------------------------------

__global__ void hist_k(const int* __restrict__ dst, int* __restrict__ counts, int E) {
    int e = blockIdx.x * blockDim.x + threadIdx.x;
    if (e < E) atomicAdd(&counts[dst[e]], 1);
}

__global__ void scan1_k(const int* __restrict__ counts, int* __restrict__ offs,
                        int* __restrict__ bsum, int n) {
    __shared__ int tmp[SCAN_B];
    int i = blockIdx.x * SCAN_B + threadIdx.x;
    int v = (i < n) ? counts[i] : 0;
    tmp[threadIdx.x] = v;
    __syncthreads();
    for (int off = 1; off < SCAN_B; off <<= 1) {
        int t = (threadIdx.x >= off) ? tmp[threadIdx.x - off] : 0;
        __syncthreads();
        tmp[threadIdx.x] += t;
        __syncthreads();
    }
    if (i < n) offs[i] = tmp[threadIdx.x] - v;   // local exclusive
    if (threadIdx.x == SCAN_B - 1) bsum[blockIdx.x] = tmp[SCAN_B - 1];
}

__global__ void scan2_k(int* __restrict__ bsum, int* __restrict__ total_out, int nb) {
    if (threadIdx.x == 0 && blockIdx.x == 0) {
        int run = 0;
        for (int b = 0; b < nb; ++b) { int v = bsum[b]; bsum[b] = run; run += v; }
        *total_out = run;
    }
}

__global__ void scan3_k(const int* __restrict__ bsum, int* __restrict__ offs,
                        const int* __restrict__ counts, int* __restrict__ cursor,
                        int* __restrict__ noin, int* __restrict__ noin_cnt, int n) {
    int i = blockIdx.x * blockDim.x + threadIdx.x;
    if (i < n) {
        int o = offs[i] + bsum[i / SCAN_B];
        offs[i] = o;
        cursor[i] = o;
        if (counts[i] == 0) noin[atomicAdd(noin_cnt, 1)] = i;
    }
}

__global__ void scatter_k(const int* __restrict__ dst, const int* __restrict__ src,
                          const int* __restrict__ etype, int* __restrict__ cursor,
                          u32* __restrict__ epack, int E) {
    int e = blockIdx.x * blockDim.x + threadIdx.x;
    if (e < E) {
        int p = atomicAdd(&cursor[dst[e]], 1);
        epack[p] = (u32)src[e] | ((u32)etype[e] << 17);
    }
}

// ---- h0b = bf16(init_ent_emb[node_id]), 2 nodes per block ----------------

__global__ void gather_k(const float* __restrict__ init, const int* __restrict__ nid,
                         u16* __restrict__ hb, int N) {
    int half = threadIdx.x >> 7;
    int t = threadIdx.x & 127;
    int v = blockIdx.x * 2 + half;
    if (v >= N || t >= 100) return;
    const float* srcp = &init[(size_t)nid[v] * D + 2 * t];
    u32 o = f2bf(srcp[0]) | (f2bf(srcp[1]) << 16);
    *(u32*)&hb[(size_t)v * D + 2 * t] = o;
}

// ---- weight prep ---------------------------------------------------------

__global__ void relb_k(const float* __restrict__ rel, u16* __restrict__ relb, int n) {
    int i = blockIdx.x * blockDim.x + threadIdx.x;
    if (i < n) relb[i] = (u16)f2bf(rel[i]);
}

// Bt[l][c][k] bf16, c in [0,256) zero-padded, k in [0,400)
__global__ void bt_k(const float* __restrict__ Wn, const float* __restrict__ Wl,
                     u16* __restrict__ Bt) {
    int idx = blockIdx.x * blockDim.x + threadIdx.x;
    if (idx >= 2 * 256 * 400) return;
    int l = idx / 102400;
    int rem = idx % 102400;
    int c = rem / 400;
    int k = rem % 400;
    float v = 0.0f;
    if (c < 200)
        v = (k < 200) ? Wn[(size_t)l * 40000 + k * 200 + c]
                      : Wl[(size_t)l * 40000 + (k - 200) * 200 + c];
    Bt[idx] = (u16)f2bf(v);
}

// ---- segment aggregation (bf16 in / bf16 out, fp32 accum) ---------------
// aggb[v] = bf16( norm[v] * sum_e (hb[src_e] + relb[etype_e]) )

__global__ void agg_k(const u16* __restrict__ hb, const u16* __restrict__ relb,
                      const u32* __restrict__ epack, const int* __restrict__ offsets,
                      const float* __restrict__ norm, u16* __restrict__ aggb, int N) {
    int half = threadIdx.x >> 7;
    int t = threadIdx.x & 127;
    int v = blockIdx.x * 2 + half;
    if (v >= N || t >= 100) return;
    int beg = offsets[v], end = offsets[v + 1];
    float ax = 0.0f, ay = 0.0f;
    for (int i = beg; i < end; ++i) {
        u32 p = epack[i];
        int s = p & 0x1FFFF;
        int r = p >> 17;
        u32 hv = *(const u32*)&hb[(size_t)s * D + 2 * t];
        u32 rv = *(const u32*)&relb[(size_t)r * D + 2 * t];
        ax += bf2f(hv & 0xffffu) + bf2f(rv & 0xffffu);
        ay += bf2f(hv >> 16) + bf2f(rv >> 16);
    }
    float nv = norm[v];
    u32 o = f2bf(ax * nv) | (f2bf(ay * nv) << 16);
    *(u32*)&aggb[(size_t)v * D + 2 * t] = o;
}

// ---- MFMA GEMM: out = rrelu([aggb | hb] @ Bt^T) -------------------------
// M x K400 x C200(pad 256). 64x64 tile, 4 waves in 2x2, each 32x32.

__global__ __launch_bounds__(256) void gemm_k(
        const u16* __restrict__ Aagg, const u16* __restrict__ Ah,
        const u16* __restrict__ Bt,
        float* __restrict__ outF, u16* __restrict__ outB, int M) {
    __shared__ __align__(16) u16 As[64][40];
    __shared__ __align__(16) u16 Bs[64][40];
    int tid = threadIdx.x;
    int lane = tid & 63;
    int wave = tid >> 6;
    int wr = (wave >> 1) * 32;
    int wc = (wave & 1) * 32;
    int rowBase = blockIdx.x * 64;
    int colBase = blockIdx.y * 64;

    f32x4 acc[2][2] = {};

    int sr = tid >> 2;          // 0..63 staging row (A) / col (B)
    int kg = (tid & 3) * 8;     // k offset within 32-k tile

    int m = lane & 15;
    int kq = (lane >> 4) * 8;

    for (int k0 = 0; k0 < 400; k0 += 32) {
        int k8 = k0 + kg;
        // stage A (row-major [row][k])
        if (rowBase + sr < M && k8 < 400) {
            const u16* sp = (k8 < 200) ? &Aagg[(size_t)(rowBase + sr) * 200 + k8]
                                       : &Ah[(size_t)(rowBase + sr) * 200 + (k8 - 200)];
            *(int4*)&As[sr][kg] = *(const int4*)sp;
        } else {
            *(int4*)&As[sr][kg] = int4{0, 0, 0, 0};
        }
        // stage B ([col][k], Bt already transposed+padded)
        if (k8 < 400) {
            *(int4*)&Bs[sr][kg] = *(const int4*)&Bt[(size_t)(colBase + sr) * 400 + k8];
        } else {
            *(int4*)&Bs[sr][kg] = int4{0, 0, 0, 0};
        }
        __syncthreads();

        bf16x8 aF0 = *(bf16x8*)&As[wr + m][kq];
        bf16x8 aF1 = *(bf16x8*)&As[wr + 16 + m][kq];
        bf16x8 bF0 = *(bf16x8*)&Bs[wc + m][kq];
        bf16x8 bF1 = *(bf16x8*)&Bs[wc + 16 + m][kq];
        acc[0][0] = __builtin_amdgcn_mfma_f32_16x16x32_bf16(aF0, bF0, acc[0][0], 0, 0, 0);
        acc[0][1] = __builtin_amdgcn_mfma_f32_16x16x32_bf16(aF0, bF1, acc[0][1], 0, 0, 0);
        acc[1][0] = __builtin_amdgcn_mfma_f32_16x16x32_bf16(aF1, bF0, acc[1][0], 0, 0, 0);
        acc[1][1] = __builtin_amdgcn_mfma_f32_16x16x32_bf16(aF1, bF1, acc[1][1], 0, 0, 0);
        __syncthreads();
    }

    // epilogue: C/D map col=lane&15, row=(lane>>4)*4+reg
    int cRow = (lane >> 4) * 4;
    int cCol = lane & 15;
#pragma unroll
    for (int i = 0; i < 2; ++i) {
#pragma unroll
        for (int j = 0; j < 2; ++j) {
            int col = colBase + wc + j * 16 + cCol;
            if (col >= 200) continue;
#pragma unroll
            for (int r = 0; r < 4; ++r) {
                int row = rowBase + wr + i * 16 + cRow + r;
                if (row < M) {
                    float val = rrelu(acc[i][j][r]);
                    if (outF) outF[(size_t)row * 200 + col] = val;
                    if (outB) outB[(size_t)row * 200 + col] = (u16)f2bf(val);
                }
            }
        }
    }
}

// ---- fixup for in-degree-0 nodes: out[v] = rrelu(h[v] @ We) -------------

__global__ void fixup_k(const u16* __restrict__ hb, const float* __restrict__ We,
                        const int* __restrict__ noin, const int* __restrict__ noin_cnt,
                        float* __restrict__ outF, u16* __restrict__ outB) {
    int cnt = *noin_cnt;
    for (int i = blockIdx.x; i < cnt; i += gridDim.x) {
        int v = noin[i];
        int j = threadIdx.x;
        if (j < D) {
            float acc = 0.0f;
            for (int k = 0; k < D; ++k)
                acc += bf2f(hb[(size_t)v * D + k]) * We[(size_t)k * D + j];
            float r = rrelu(acc);
            if (outF) outF[(size_t)v * D + j] = r;
            if (outB) outB[(size_t)v * D + j] = (u16)f2bf(r);
        }
    }
}

extern "C" void kernel_launch(void* const* d_in, const int* in_sizes, int n_in,
                              void* d_out, int out_size, void* d_ws, size_t ws_size,
                              hipStream_t stream) {
    const float* init  = (const float*)d_in[0];
    const float* rel   = (const float*)d_in[1];
    const float* Wn    = (const float*)d_in[2];
    const float* Wl    = (const float*)d_in[3];
    const float* We    = (const float*)d_in[4];
    const float* norm  = (const float*)d_in[5];
    const int* src     = (const int*)d_in[6];
    const int* dst     = (const int*)d_in[7];
    const int* etype   = (const int*)d_in[8];
    const int* node_id = (const int*)d_in[9];
    float* out = (float*)d_out;

    int N = in_sizes[5];
    int E = in_sizes[6];
    int nb = (N + SCAN_B - 1) / SCAN_B;

    // workspace carve
    char* w = (char*)d_ws;
    u16* hb0  = (u16*)w; w += (size_t)N * D * sizeof(u16);
    u16* hb1  = (u16*)w; w += (size_t)N * D * sizeof(u16);
    u16* aggb = (u16*)w; w += (size_t)N * D * sizeof(u16);
    u16* relb = (u16*)w; w += (size_t)500 * D * sizeof(u16) + 256;
    u16* Bt   = (u16*)w; w += (size_t)2 * 256 * 400 * sizeof(u16) + 256;
    int* counts  = (int*)w; w += (size_t)N * sizeof(int);
    int* offsets = (int*)w; w += (size_t)(N + 1) * sizeof(int);
    int* cursor  = (int*)w; w += (size_t)N * sizeof(int);
    u32* epack   = (u32*)w; w += (size_t)E * sizeof(u32);
    int* noin    = (int*)w; w += (size_t)N * sizeof(int);
    int* noin_cnt = (int*)w; w += 256;
    int* bsum    = (int*)w; w += (size_t)nb * sizeof(int) + 256;

    hipMemsetAsync(counts, 0, (size_t)N * sizeof(int), stream);
    hipMemsetAsync(noin_cnt, 0, sizeof(int), stream);

    hist_k<<<(E + 255) / 256, 256, 0, stream>>>(dst, counts, E);
    scan1_k<<<nb, SCAN_B, 0, stream>>>(counts, offsets, bsum, N);
    scan2_k<<<1, 64, 0, stream>>>(bsum, offsets + N, nb);
    scan3_k<<<(N + 255) / 256, 256, 0, stream>>>(bsum, offsets, counts, cursor,
                                                 noin, noin_cnt, N);
    scatter_k<<<(E + 255) / 256, 256, 0, stream>>>(dst, src, etype, cursor, epack, E);

    gather_k<<<(N + 1) / 2, 256, 0, stream>>>(init, node_id, hb0, N);
    relb_k<<<(500 * D + 255) / 256, 256, 0, stream>>>(rel, relb, 500 * D);
    bt_k<<<(2 * 256 * 400 + 255) / 256, 256, 0, stream>>>(Wn, Wl, Bt);

    dim3 gg((N + 63) / 64, 4);

    // layer 0: bf16 output only
    agg_k<<<(N + 1) / 2, 256, 0, stream>>>(hb0, relb, epack, offsets, norm, aggb, N);
    gemm_k<<<gg, 256, 0, stream>>>(aggb, hb0, Bt, nullptr, hb1, N);
    fixup_k<<<64, 256, 0, stream>>>(hb0, We, noin, noin_cnt, nullptr, hb1);

    // layer 1: fp32 output to d_out
    agg_k<<<(N + 1) / 2, 256, 0, stream>>>(hb1, relb, epack, offsets, norm, aggb, N);
    gemm_k<<<gg, 256, 0, stream>>>(aggb, hb1, Bt + 256 * 400, out, nullptr, N);
    fixup_k<<<64, 256, 0, stream>>>(hb1, We + D * D, noin, noin_cnt, out, nullptr);
}

// Round 3
// 473.826 us; speedup vs baseline: 2.8047x; 1.3201x over previous
//
#include <hip/hip_runtime.h>

#define D 200
#define RRELU_SLOPE 0.22916666666666666f
#define SCAN_B 1024

typedef unsigned short u16;
typedef unsigned int u32;

using bf16x8 = __attribute__((ext_vector_type(8))) short;
using f32x4  = __attribute__((ext_vector_type(4))) float;

__device__ __forceinline__ float rrelu(float x) {
    return x >= 0.0f ? x : x * RRELU_SLOPE;
}
__device__ __forceinline__ float bf2f(u32 u) {
    union { u32 i; float f; } c; c.i = u << 16; return c.f;
}
__device__ __forceinline__ u32 f2bf(float f) {
    union { float f; u32 i; } c; c.f = f;
    return (c.i + 0x7fffu + ((c.i >> 16) & 1u)) >> 16;
}
__device__ __forceinline__ void gll16(const void* g, void* l) {
    __builtin_amdgcn_global_load_lds((const __attribute__((address_space(1))) void*)g,
                                     (__attribute__((address_space(3))) void*)l,
                                     16, 0, 0);
}

// ---- CSR build ----------------------------------------------------------

__global__ void hist_k(const int* __restrict__ dst, int* __restrict__ counts, int E) {
    int e = blockIdx.x * blockDim.x + threadIdx.x;
    if (e < E) atomicAdd(&counts[dst[e]], 1);
}

__global__ void scan1_k(const int* __restrict__ counts, int* __restrict__ offs,
                        int* __restrict__ bsum, int n) {
    __shared__ int tmp[SCAN_B];
    int i = blockIdx.x * SCAN_B + threadIdx.x;
    int v = (i < n) ? counts[i] : 0;
    tmp[threadIdx.x] = v;
    __syncthreads();
    for (int off = 1; off < SCAN_B; off <<= 1) {
        int t = (threadIdx.x >= off) ? tmp[threadIdx.x - off] : 0;
        __syncthreads();
        tmp[threadIdx.x] += t;
        __syncthreads();
    }
    if (i < n) offs[i] = tmp[threadIdx.x] - v;   // local exclusive
    if (threadIdx.x == SCAN_B - 1) bsum[blockIdx.x] = tmp[SCAN_B - 1];
}

__global__ void scan2_k(int* __restrict__ bsum, int* __restrict__ total_out, int nb) {
    if (threadIdx.x == 0 && blockIdx.x == 0) {
        int run = 0;
        for (int b = 0; b < nb; ++b) { int v = bsum[b]; bsum[b] = run; run += v; }
        *total_out = run;
    }
}

__global__ void scan3_k(const int* __restrict__ bsum, int* __restrict__ offs,
                        const int* __restrict__ counts, int* __restrict__ cursor,
                        int* __restrict__ noin, int* __restrict__ noin_cnt, int n) {
    int i = blockIdx.x * blockDim.x + threadIdx.x;
    if (i < n) {
        int o = offs[i] + bsum[i / SCAN_B];
        offs[i] = o;
        cursor[i] = o;
        if (counts[i] == 0) noin[atomicAdd(noin_cnt, 1)] = i;
    }
}

__global__ void scatter_k(const int* __restrict__ dst, const int* __restrict__ src,
                          const int* __restrict__ etype, int* __restrict__ cursor,
                          u32* __restrict__ epack, int E) {
    int e = blockIdx.x * blockDim.x + threadIdx.x;
    if (e < E) {
        int p = atomicAdd(&cursor[dst[e]], 1);
        epack[p] = (u32)src[e] | ((u32)etype[e] << 17);
    }
}

// ---- h0b = bf16(init_ent_emb[node_id]), 1 node per wave ------------------

__global__ void gather_k(const float* __restrict__ init, const int* __restrict__ nid,
                         u16* __restrict__ hb, int N) {
    int lane = threadIdx.x & 63;
    int v = blockIdx.x * 4 + (threadIdx.x >> 6);
    if (v >= N || lane >= 50) return;
    float4 f = *(const float4*)(init + (size_t)nid[v] * D + lane * 4);
    uint2 o;
    o.x = f2bf(f.x) | (f2bf(f.y) << 16);
    o.y = f2bf(f.z) | (f2bf(f.w) << 16);
    *(uint2*)(hb + (size_t)v * D + lane * 4) = o;
}

// ---- weight prep ---------------------------------------------------------

__global__ void relb_k(const float* __restrict__ rel, u16* __restrict__ relb, int n) {
    int i = blockIdx.x * blockDim.x + threadIdx.x;
    if (i < n) relb[i] = (u16)f2bf(rel[i]);
}

// Bt[l][c][k] bf16: c in [0,256) (>=200 zero), k in [0,416) (>=400 zero)
__global__ void bt_k(const float* __restrict__ Wn, const float* __restrict__ Wl,
                     u16* __restrict__ Bt) {
    int idx = blockIdx.x * blockDim.x + threadIdx.x;
    if (idx >= 2 * 256 * 416) return;
    int l = idx / (256 * 416);
    int rem = idx % (256 * 416);
    int c = rem / 416;
    int k = rem % 416;
    float v = 0.0f;
    if (c < 200 && k < 400)
        v = (k < 200) ? Wn[(size_t)l * 40000 + k * 200 + c]
                      : Wl[(size_t)l * 40000 + (k - 200) * 200 + c];
    Bt[idx] = (u16)f2bf(v);
}

// ---- generic segment gather-sum -----------------------------------------
// outb[v] = bf16( (sum_e table[idx(epack_e)] + addb[v]) * norm[v] )
// idx = useHi ? p>>17 : p&0x1FFFF.  One wave per node, lanes 0..49 x 4 elems.

__global__ void gagg_k(const u16* __restrict__ table, const u32* __restrict__ epack,
                       const int* __restrict__ offsets, const float* __restrict__ norm,
                       const u16* __restrict__ addb, u16* __restrict__ outb,
                       int N, int useHi) {
    int lane = threadIdx.x & 63;
    int v = blockIdx.x * 4 + (threadIdx.x >> 6);
    if (v >= N || lane >= 50) return;
    int beg = offsets[v], end = offsets[v + 1];
    float a0 = 0, a1 = 0, a2 = 0, a3 = 0;
    size_t lo = (size_t)lane * 4;
#define ROWI(p) ((size_t)(useHi ? ((p) >> 17) : ((p) & 0x1FFFF)) * D + lo)
#define ACC8(q) { a0 += bf2f(q.x & 0xffffu); a1 += bf2f(q.x >> 16); \
                  a2 += bf2f(q.y & 0xffffu); a3 += bf2f(q.y >> 16); }
    int i = beg;
    for (; i + 4 <= end; i += 4) {
        u32 p0 = epack[i], p1 = epack[i + 1], p2 = epack[i + 2], p3 = epack[i + 3];
        uint2 q0 = *(const uint2*)(table + ROWI(p0));
        uint2 q1 = *(const uint2*)(table + ROWI(p1));
        uint2 q2 = *(const uint2*)(table + ROWI(p2));
        uint2 q3 = *(const uint2*)(table + ROWI(p3));
        ACC8(q0); ACC8(q1); ACC8(q2); ACC8(q3);
    }
    for (; i < end; ++i) {
        u32 p = epack[i];
        uint2 q = *(const uint2*)(table + ROWI(p));
        ACC8(q);
    }
    if (addb) {
        uint2 q = *(const uint2*)(addb + (size_t)v * D + lo);
        ACC8(q);
    }
    float nv = norm ? norm[v] : 1.0f;
    uint2 o;
    o.x = f2bf(a0 * nv) | (f2bf(a1 * nv) << 16);
    o.y = f2bf(a2 * nv) | (f2bf(a3 * nv) << 16);
    *(uint2*)(outb + (size_t)v * D + lo) = o;
#undef ROWI
#undef ACC8
}

// ---- MFMA GEMM: out = rrelu([aggb | hb] @ Bt^T) -------------------------
// 128x64 tile, 256 threads (4 waves 2x2, wave = 64x32), K=416 (B zero-padded).
// global_load_lds width-16 staging into unpadded [row][32] LDS.

__global__ __launch_bounds__(256) void gemm_k(
        const u16* __restrict__ Aagg, const u16* __restrict__ Ah,
        const u16* __restrict__ Bt,
        float* __restrict__ outF, u16* __restrict__ outB, int M) {
    __shared__ __align__(16) u16 As[128 * 32];
    __shared__ __align__(16) u16 Bs[64 * 32];
    int tid = threadIdx.x;
    int lane = tid & 63;
    int wave = tid >> 6;
    int rowBase = blockIdx.x * 128;
    int colBase = blockIdx.y * 64;
    int wr = (wave >> 1) * 64;
    int wc = (wave & 1) * 32;
    int m = lane & 15;
    int kq = (lane >> 4) * 8;

    int srow = tid >> 2;            // 0..63
    int kg = (tid & 3) * 8;

    u16* ldsA0 = As + ((size_t)(wave * 64) * 8);
    u16* ldsA1 = As + ((size_t)(256 + wave * 64) * 8);
    u16* ldsB  = Bs + ((size_t)(wave * 64) * 8);

    f32x4 acc[4][2] = {};

    for (int k0 = 0; k0 < 416; k0 += 32) {
        int k = k0 + kg;
        // A rows srow and srow+64 (chunks are 8 k-elems, never straddle 200)
        {
            const u16* g0 = (k < 200) ? Aagg + (size_t)(rowBase + srow) * D + k
                                      : Ah + (size_t)(rowBase + srow) * D + (k - 200);
            gll16(g0, ldsA0);
            const u16* g1 = (k < 200) ? Aagg + (size_t)(rowBase + srow + 64) * D + k
                                      : Ah + (size_t)(rowBase + srow + 64) * D + (k - 200);
            gll16(g1, ldsA1);
            const u16* gb = Bt + (size_t)(colBase + srow) * 416 + k;
            gll16(gb, ldsB);
        }
        __syncthreads();

        bf16x8 a0 = *(const bf16x8*)(As + (wr + m) * 32 + kq);
        bf16x8 a1 = *(const bf16x8*)(As + (wr + 16 + m) * 32 + kq);
        bf16x8 a2 = *(const bf16x8*)(As + (wr + 32 + m) * 32 + kq);
        bf16x8 a3 = *(const bf16x8*)(As + (wr + 48 + m) * 32 + kq);
        bf16x8 b0 = *(const bf16x8*)(Bs + (wc + m) * 32 + kq);
        bf16x8 b1 = *(const bf16x8*)(Bs + (wc + 16 + m) * 32 + kq);
        acc[0][0] = __builtin_amdgcn_mfma_f32_16x16x32_bf16(a0, b0, acc[0][0], 0, 0, 0);
        acc[0][1] = __builtin_amdgcn_mfma_f32_16x16x32_bf16(a0, b1, acc[0][1], 0, 0, 0);
        acc[1][0] = __builtin_amdgcn_mfma_f32_16x16x32_bf16(a1, b0, acc[1][0], 0, 0, 0);
        acc[1][1] = __builtin_amdgcn_mfma_f32_16x16x32_bf16(a1, b1, acc[1][1], 0, 0, 0);
        acc[2][0] = __builtin_amdgcn_mfma_f32_16x16x32_bf16(a2, b0, acc[2][0], 0, 0, 0);
        acc[2][1] = __builtin_amdgcn_mfma_f32_16x16x32_bf16(a2, b1, acc[2][1], 0, 0, 0);
        acc[3][0] = __builtin_amdgcn_mfma_f32_16x16x32_bf16(a3, b0, acc[3][0], 0, 0, 0);
        acc[3][1] = __builtin_amdgcn_mfma_f32_16x16x32_bf16(a3, b1, acc[3][1], 0, 0, 0);
        __syncthreads();
    }

    // epilogue: C/D map col=lane&15, row=(lane>>4)*4+reg
    int cRow = (lane >> 4) * 4;
    int cCol = lane & 15;
#pragma unroll
    for (int i = 0; i < 4; ++i) {
#pragma unroll
        for (int j = 0; j < 2; ++j) {
            int col = colBase + wc + j * 16 + cCol;
            if (col >= 200) continue;
#pragma unroll
            for (int r = 0; r < 4; ++r) {
                int row = rowBase + wr + i * 16 + cRow + r;
                if (row < M) {
                    float val = rrelu(acc[i][j][r]);
                    if (outF) outF[(size_t)row * D + col] = val;
                    if (outB) outB[(size_t)row * D + col] = (u16)f2bf(val);
                }
            }
        }
    }
}

// ---- fixup for in-degree-0 nodes: out[v] = rrelu(h[v] @ We) -------------

__global__ void fixup_k(const u16* __restrict__ hb, const float* __restrict__ We,
                        const int* __restrict__ noin, const int* __restrict__ noin_cnt,
                        float* __restrict__ outF, u16* __restrict__ outB) {
    int cnt = *noin_cnt;
    for (int i = blockIdx.x; i < cnt; i += gridDim.x) {
        int v = noin[i];
        int j = threadIdx.x;
        if (j < D) {
            float acc = 0.0f;
            for (int k = 0; k < D; ++k)
                acc += bf2f(hb[(size_t)v * D + k]) * We[(size_t)k * D + j];
            float r = rrelu(acc);
            if (outF) outF[(size_t)v * D + j] = r;
            if (outB) outB[(size_t)v * D + j] = (u16)f2bf(r);
        }
    }
}

extern "C" void kernel_launch(void* const* d_in, const int* in_sizes, int n_in,
                              void* d_out, int out_size, void* d_ws, size_t ws_size,
                              hipStream_t stream) {
    const float* init  = (const float*)d_in[0];
    const float* rel   = (const float*)d_in[1];
    const float* Wn    = (const float*)d_in[2];
    const float* Wl    = (const float*)d_in[3];
    const float* We    = (const float*)d_in[4];
    const float* norm  = (const float*)d_in[5];
    const int* src     = (const int*)d_in[6];
    const int* dst     = (const int*)d_in[7];
    const int* etype   = (const int*)d_in[8];
    const int* node_id = (const int*)d_in[9];
    float* out = (float*)d_out;

    int N = in_sizes[5];
    int E = in_sizes[6];
    int nb = (N + SCAN_B - 1) / SCAN_B;
    size_t NP = (size_t)N + 256;           // row padding for unguarded tile reads

    // workspace carve (256B aligned chunks)
    char* w = (char*)d_ws;
    auto carve = [&](size_t bytes) {
        char* p = w;
        w += (bytes + 255) & ~(size_t)255;
        return p;
    };
    u16* hb0     = (u16*)carve(NP * D * sizeof(u16));
    u16* hb1     = (u16*)carve(NP * D * sizeof(u16));
    u16* aggb    = (u16*)carve(NP * D * sizeof(u16));
    u16* relsumb = (u16*)carve((size_t)N * D * sizeof(u16));
    u16* relb    = (u16*)carve((size_t)500 * D * sizeof(u16));
    u16* Bt      = (u16*)carve((size_t)2 * 256 * 416 * sizeof(u16));
    int* counts  = (int*)carve((size_t)N * sizeof(int));
    int* offsets = (int*)carve((size_t)(N + 1) * sizeof(int));
    int* cursor  = (int*)carve((size_t)N * sizeof(int));
    u32* epack   = (u32*)carve((size_t)E * sizeof(u32));
    int* noin    = (int*)carve((size_t)N * sizeof(int));
    int* noin_cnt = (int*)carve(sizeof(int));
    int* bsum    = (int*)carve((size_t)nb * sizeof(int));

    hipMemsetAsync(counts, 0, (size_t)N * sizeof(int), stream);
    hipMemsetAsync(noin_cnt, 0, sizeof(int), stream);

    hist_k<<<(E + 255) / 256, 256, 0, stream>>>(dst, counts, E);
    scan1_k<<<nb, SCAN_B, 0, stream>>>(counts, offsets, bsum, N);
    scan2_k<<<1, 64, 0, stream>>>(bsum, offsets + N, nb);
    scan3_k<<<(N + 255) / 256, 256, 0, stream>>>(bsum, offsets, counts, cursor,
                                                 noin, noin_cnt, N);
    scatter_k<<<(E + 255) / 256, 256, 0, stream>>>(dst, src, etype, cursor, epack, E);

    gather_k<<<(N + 3) / 4, 256, 0, stream>>>(init, node_id, hb0, N);
    relb_k<<<(500 * D + 255) / 256, 256, 0, stream>>>(rel, relb, 500 * D);
    bt_k<<<(2 * 256 * 416 + 255) / 256, 256, 0, stream>>>(Wn, Wl, Bt);

    // relsumb[v] = sum_e rel[etype_e]  (layer-invariant)
    gagg_k<<<(N + 3) / 4, 256, 0, stream>>>(relb, epack, offsets, nullptr,
                                            nullptr, relsumb, N, 1);

    dim3 gg((N + 127) / 128, 4);

    // layer 0: bf16 output only
    gagg_k<<<(N + 3) / 4, 256, 0, stream>>>(hb0, epack, offsets, norm,
                                            relsumb, aggb, N, 0);
    gemm_k<<<gg, 256, 0, stream>>>(aggb, hb0, Bt, nullptr, hb1, N);
    fixup_k<<<8, 256, 0, stream>>>(hb0, We, noin, noin_cnt, nullptr, hb1);

    // layer 1: fp32 output to d_out
    gagg_k<<<(N + 3) / 4, 256, 0, stream>>>(hb1, epack, offsets, norm,
                                            relsumb, aggb, N, 0);
    gemm_k<<<gg, 256, 0, stream>>>(aggb, hb1, Bt + 256 * 416, out, nullptr, N);
    fixup_k<<<8, 256, 0, stream>>>(hb1, We + D * D, noin, noin_cnt, out, nullptr);
}